// Round 21
// baseline (115.966 us; speedup 1.0000x reference)
//
#include <hip/hip_runtime.h>
#include <cstdint>

#define B_NODES 16384
#define C_CH    64
#define I_DIM   9
#define S_SPEC  10
#define K3C     23
#define K2C     5
#define K1C     2
#define NTRI    165
#define NPAIR   45
#define NSING   9
#define NIDX    (NTRI + NPAIR + NSING)   // 219
#define NLDS    128   // rows staged in LDS; rows NLDS..218 via VECTOR loads
#define TILE_N  256   // nodes per tile (= block); 1 node/thread (r16-proven)
#define MAXT    74    // <= B/256 + S
#define NROUND  10    // ceil(MAXT/8)
#define SCAP    (MAXT * TILE_N)
#define OUT_STRIDE (4 * C_CH)
#define NHB     64    // histogram blocks

#define N3SL (NTRI * K3C)    // 3795
#define N2SL (NPAIR * K2C)   // 225
#define N1SL (NSING * K1C)   // 18
#define NUSYM (N3SL + N2SL + N1SL)  // 4038
#define TBL_THREADS (S_SPEC * C_CH * NIDX)   // 140160

typedef float v2f __attribute__((ext_vector_type(2)));
typedef float v4f __attribute__((ext_vector_type(4)));

// ============ kernel 1: prep (blocks 0..63: hist-partials; blocks 64..: usym) ============

__global__ __launch_bounds__(256) void k_prep(
        const float* __restrict__ y,
        const float* __restrict__ U3s, const float* __restrict__ U2s,
        const float* __restrict__ U1s,
        const float* __restrict__ U3v, const float* __restrict__ U2v,
        const float* __restrict__ U1v,
        int* __restrict__ species, int* __restrict__ cnt_part,
        int* __restrict__ cursor,
        float* __restrict__ us3, float* __restrict__ uv3,
        float* __restrict__ us2, float* __restrict__ uv2,
        float* __restrict__ us1, float* __restrict__ uv1) {
    int tid = threadIdx.x;
    if (blockIdx.x < NHB) {
        __shared__ int hcnt[S_SPEC];
        if (tid < S_SPEC) hcnt[tid] = 0;
        __syncthreads();
        int i = blockIdx.x * (B_NODES / NHB) + tid;   // chunk = 256 = blockDim
        {
            int e = 0; float best = -1.f;
            #pragma unroll
            for (int j = 0; j < S_SPEC; ++j) {
                float v = y[i * S_SPEC + j];
                if (v > best) { best = v; e = j; }
            }
            species[i] = e;
            atomicAdd(&hcnt[e], 1);
        }
        __syncthreads();
        if (tid < S_SPEC) cnt_part[blockIdx.x * S_SPEC + tid] = hcnt[tid];
        return;
    }
    // ---- usym blocks: 4*NUSYM threads, m = segment ----
    if (blockIdx.x == NHB && tid < S_SPEC) cursor[tid] = 0;
    int tt = (blockIdx.x - NHB) * 256 + tid;
    if (tt >= 4 * NUSYM) return;
    int m = tt / NUSYM;
    int t = tt - m * NUSYM;

    if (t < N3SL) {
        int idx = t / K3C, k = t % K3C;
        int p = 0, q = 0, r = 0, cum = 0;
        for (int p0 = 0; p0 < 9; ++p0)
            for (int q0 = p0; q0 < 9; ++q0)
                for (int r0 = q0; r0 < 9; ++r0) {
                    if (cum == idx) { p = p0; q = q0; r = r0; }
                    ++cum;
                }
        const float* src = (m == 0) ? U3s : (U3v + (size_t)(m - 1) * 729 * K3C);
        int perm[6][3] = {{p,q,r},{p,r,q},{q,p,r},{q,r,p},{r,p,q},{r,q,p}};
        float a0 = 0.f;
        for (int j = 0; j < 6; ++j) {
            bool dup = false;
            for (int j2 = 0; j2 < j; ++j2)
                if (perm[j2][0]==perm[j][0] && perm[j2][1]==perm[j][1] && perm[j2][2]==perm[j][2])
                    dup = true;
            if (dup) continue;
            int a = perm[j][0], bb = perm[j][1], i = perm[j][2];
            a0 += src[((a * 9 + bb) * 9 + i) * K3C + k];
        }
        float* dst = (m == 0) ? us3 : (uv3 + (size_t)(m - 1) * N3SL);
        dst[t] = a0;
    } else if (t < N3SL + N2SL) {
        int t2 = t - N3SL;
        int idx = t2 / K2C, k = t2 % K2C;
        int p = 0, q = 0, cum = 0;
        for (int p0 = 0; p0 < 9; ++p0)
            for (int q0 = p0; q0 < 9; ++q0) {
                if (cum == idx) { p = p0; q = q0; }
                ++cum;
            }
        const float* src = (m == 0) ? U2s : (U2v + (size_t)(m - 1) * 81 * K2C);
        float a0 = src[(p * 9 + q) * K2C + k];
        if (p != q) a0 += src[(q * 9 + p) * K2C + k];
        float* dst = (m == 0) ? us2 : (uv2 + (size_t)(m - 1) * N2SL);
        dst[t2] = a0;
    } else {
        int t1 = t - N3SL - N2SL;
        const float* src = (m == 0) ? U1s : (U1v + (size_t)(m - 1) * 9 * K1C);
        float* dst = (m == 0) ? us1 : (uv1 + (size_t)(m - 1) * N1SL);
        dst[t1] = src[t1];
    }
}

// ============ kernel 2: mid (blocks 0..63: scatter; rest: table build) ============

__global__ __launch_bounds__(256) void k_mid(
        const int* __restrict__ species, const int* __restrict__ cnt_part,
        int* __restrict__ cnt_final,
        int* __restrict__ cursor, int* __restrict__ sorted,
        const float* __restrict__ W3s, const float* __restrict__ W2s,
        const float* __restrict__ W1s,
        const float* __restrict__ W3v, const float* __restrict__ W2v,
        const float* __restrict__ W1v,
        const float* __restrict__ us3, const float* __restrict__ uv3,
        const float* __restrict__ us2, const float* __restrict__ uv2,
        const float* __restrict__ us1, const float* __restrict__ uv1,
        float* __restrict__ table) {
    int tid = threadIdx.x;
    if (blockIdx.x < B_NODES / 256) {
        __shared__ int scnt[S_SPEC], sseg[S_SPEC];
        if (tid < S_SPEC) {
            int s = 0;
            for (int w = 0; w < NHB; ++w) s += cnt_part[w * S_SPEC + tid];
            scnt[tid] = s;
            if (blockIdx.x == 0) cnt_final[tid] = s;
        }
        __syncthreads();
        if (tid == 0) {
            int run = 0;
            for (int j = 0; j < S_SPEC; ++j) {
                sseg[j] = run;
                run += ((scnt[j] + TILE_N - 1) / TILE_N) * TILE_N;
            }
        }
        __syncthreads();
        int b = blockIdx.x * 256 + tid;
        int e = species[b];
        int lane = tid & 63;
        unsigned long long lanebit = 1ull << lane;
        for (int j = 0; j < S_SPEC; ++j) {
            unsigned long long m = __ballot(e == j);
            if (m == 0ull) continue;
            int leader = __ffsll(m) - 1;
            int base = 0;
            if (lane == leader) base = atomicAdd(&cursor[j], __popcll(m));
            base = __shfl(base, leader);
            if (e == j) {
                int pos = base + __popcll(m & (lanebit - 1ull));
                sorted[sseg[j] + pos] = b;
            }
        }
        return;
    }
    // ---- table build: t = (e*64 + c)*NIDX + row; lanes span row ----
    int t = (blockIdx.x - B_NODES / 256) * 256 + tid;
    if (t >= TBL_THREADS) return;
    int row = t % NIDX;
    int ec  = t / NIDX;
    int c = ec & (C_CH - 1), e = ec >> 6;

    int type = -1, pp = 0, pidx = 0, tidx = 0;
    {
        int cum = 0, pcount = 0, tcount = 0;
        for (int p0 = 0; p0 < 9; ++p0) {
            if (cum == row) { type = 0; pp = p0; }
            ++cum;
            for (int q0 = p0; q0 < 9; ++q0) {
                if (cum == row) { type = 1; pidx = pcount; }
                ++cum; ++pcount;
                for (int r0 = q0; r0 < 9; ++r0) {
                    if (cum == row) { type = 2; tidx = tcount; }
                    ++cum; ++tcount;
                }
            }
        }
    }

    float acc0 = 0.f, acc1 = 0.f, acc2 = 0.f, acc3 = 0.f;
    if (type == 2) {
        const float* u0 = us3 + tidx * K3C;
        const float* u1 = uv3 + 0 * N3SL + tidx * K3C;
        const float* u2 = uv3 + 1 * N3SL + tidx * K3C;
        const float* u3 = uv3 + 2 * N3SL + tidx * K3C;
        const float* Ws = W3s + (size_t)e * K3C * C_CH + c;
        const float* Wv = W3v + (size_t)e * K3C * C_CH + c;
        #pragma unroll
        for (int k = 0; k < K3C; ++k) {
            float ws = Ws[k * C_CH], wv = Wv[k * C_CH];
            acc0 += u0[k] * ws;
            acc1 += u1[k] * wv;
            acc2 += u2[k] * wv;
            acc3 += u3[k] * wv;
        }
    } else if (type == 1) {
        const float* u0 = us2 + pidx * K2C;
        const float* u1 = uv2 + 0 * N2SL + pidx * K2C;
        const float* u2 = uv2 + 1 * N2SL + pidx * K2C;
        const float* u3 = uv2 + 2 * N2SL + pidx * K2C;
        const float* Ws = W2s + (size_t)e * K2C * C_CH + c;
        const float* Wv = W2v + (size_t)e * K2C * C_CH + c;
        #pragma unroll
        for (int k = 0; k < K2C; ++k) {
            float ws = Ws[k * C_CH], wv = Wv[k * C_CH];
            acc0 += u0[k] * ws;
            acc1 += u1[k] * wv;
            acc2 += u2[k] * wv;
            acc3 += u3[k] * wv;
        }
    } else {
        const float* u0 = us1 + pp * K1C;
        const float* u1 = uv1 + 0 * N1SL + pp * K1C;
        const float* u2 = uv1 + 1 * N1SL + pp * K1C;
        const float* u3 = uv1 + 2 * N1SL + pp * K1C;
        const float* Ws = W1s + (size_t)e * K1C * C_CH + c;
        const float* Wv = W1v + (size_t)e * K1C * C_CH + c;
        #pragma unroll
        for (int k = 0; k < K1C; ++k) {
            float ws = Ws[k * C_CH], wv = Wv[k * C_CH];
            acc0 += u0[k] * ws;
            acc1 += u1[k] * wv;
            acc2 += u2[k] * wv;
            acc3 += u3[k] * wv;
        }
    }
    *(v4f*)(table + (size_t)t * 4) = (v4f){acc0, acc1, acc2, acc3};
}

// ============ kernel 3: main — DS + VMEM dual-path table reads ============
// r20's scalar tail FAILED because SMEM shares lgkmcnt with DS (SMEM is
// out-of-order -> every s_load wait is lgkmcnt(0) -> drains the DS queue;
// no overlap). Fix: tail rows via VECTOR loads (vzero-forced per-lane
// address, r10-proven codegen: global_load_dwordx4 from one VGPR base +
// imm offset, uniform address -> L1 broadcast). global_* counts in vmcnt
// ONLY -> true concurrency with the DS pipe. Rows 0..127 via LDS (DS pipe,
// ~1090cyc/wave); rows 128..218 via VMEM, L1-resident (11.6KB/CU), issued
// ahead under vmcnt and consumed between ds_reads. Offsets 2048..3504B fit
// the 13-bit imm. Ternary folds statically after full unroll.

__global__ __launch_bounds__(256) void k_main(
        const float* __restrict__ x, const float* __restrict__ table,
        const int* __restrict__ sorted, const int* __restrict__ cnt,
        float* __restrict__ out) {
    __shared__ float xs[TILE_N * 9];   // 9.2KB
    __shared__ v4f   ts[NLDS];         // 2KB table slice (rows 0..127)

    int f = blockIdx.x;
    int xcd = f & 7;
    int j = f >> 3;                    // 0 .. NROUND*64-1
    int t = (j >> 6) * 8 + xcd;        // tiles round-robin across XCDs
    int c = j & 63;
    // derive tile species + valid count from cnt (wave-uniform 10-iter prefix)
    int e = -1, run = 0, tstart = 0, ecnt = 0;
    #pragma unroll
    for (int s = 0; s < S_SPEC; ++s) {
        int cs = cnt[s];
        int tiles = (cs + TILE_N - 1) / TILE_N;
        if (t >= run && t < run + tiles) { e = s; tstart = run; ecnt = cs; }
        run += tiles;
    }
    if (e < 0) return;
    int valid = ecnt - (t - tstart) * TILE_N;
    if (valid > TILE_N) valid = TILE_N;
    int tid = threadIdx.x;

    int slice = __builtin_amdgcn_readfirstlane(e * C_CH + c);
    const v4f* __restrict__ Tg = (const v4f*)table + (size_t)slice * NIDX;

    // stage rows 0..NLDS-1 into LDS
    if (tid < NLDS) ts[tid] = Tg[tid];

    // stage x: per node 36B contiguous
    for (int s = tid; s < TILE_N * 9; s += 256) {
        int n = s / 9, i = s - n * 9;
        float v = 0.f;
        if (n < valid) {
            int b = sorted[t * TILE_N + n];
            v = x[((size_t)b * C_CH + c) * I_DIM + i];
        }
        xs[n * 9 + i] = v;   // stride 9, gcd(9,32)=1 -> conflict-free
    }
    __syncthreads();

    float xr[9];
    #pragma unroll
    for (int i = 0; i < 9; ++i) xr[i] = xs[tid * 9 + i];

    // opaque VGPR zero -> VECTOR addressing for tail rows (vmcnt pipe)
    int vzero;
    asm volatile("v_mov_b32 %0, 0" : "=v"(vzero));
    const v4f* __restrict__ Tv = (const v4f*)((const char*)Tg + vzero);

    v2f a01 = {0.f, 0.f}, a23 = {0.f, 0.f};
    int tix = 0;
    #pragma unroll
    for (int p = 0; p < 9; ++p) {
        {
            v4f rs = (tix < NLDS) ? ts[tix] : Tv[tix]; ++tix;
            a01 += (v2f){rs[0], rs[1]} * xr[p];
            a23 += (v2f){rs[2], rs[3]} * xr[p];
        }
        #pragma unroll
        for (int q = p; q < 9; ++q) {
            float m2 = xr[p] * xr[q];
            v4f rp = (tix < NLDS) ? ts[tix] : Tv[tix]; ++tix;
            a01 += (v2f){rp[0], rp[1]} * m2;
            a23 += (v2f){rp[2], rp[3]} * m2;
            #pragma unroll
            for (int r = q; r < 9; ++r) {
                float m3 = m2 * xr[r];
                v4f rt = (tix < NLDS) ? ts[tix] : Tv[tix]; ++tix;
                a01 += (v2f){rt[0], rt[1]} * m3;
                a23 += (v2f){rt[2], rt[3]} * m3;
            }
        }
    }

    if (tid >= valid) return;
    int b = sorted[t * TILE_N + tid];
    out[(size_t)b * OUT_STRIDE + c] = a01.x;
    float* ov = out + (size_t)b * OUT_STRIDE + C_CH + c * 3;
    ov[0] = a01.y; ov[1] = a23.x; ov[2] = a23.y;
}

// ============ launcher: 3 kernels, no memsets ============

extern "C" void kernel_launch(void* const* d_in, const int* in_sizes, int n_in,
                              void* d_out, int out_size, void* d_ws, size_t ws_size,
                              hipStream_t stream) {
    const float* x   = (const float*)d_in[0];
    const float* y   = (const float*)d_in[1];
    const float* U3s = (const float*)d_in[2];
    const float* U2s = (const float*)d_in[3];
    const float* U1s = (const float*)d_in[4];
    const float* W3s = (const float*)d_in[5];
    const float* W2s = (const float*)d_in[6];
    const float* W1s = (const float*)d_in[7];
    const float* U3v = (const float*)d_in[8];
    const float* U2v = (const float*)d_in[9];
    const float* U1v = (const float*)d_in[10];
    const float* W3v = (const float*)d_in[11];
    const float* W2v = (const float*)d_in[12];
    const float* W1v = (const float*)d_in[13];
    float* out = (float*)d_out;

    char* ws = (char*)d_ws;
    size_t off = 0;
    auto alloc = [&](size_t bytes) -> char* {
        char* p = ws + off;
        off = (off + bytes + 255) & ~(size_t)255;
        return p;
    };
    float* table    = (float*)alloc((size_t)S_SPEC * C_CH * NIDX * 4 * sizeof(float));
    float* us3      = (float*)alloc(N3SL * sizeof(float));
    float* uv3      = (float*)alloc(3 * N3SL * sizeof(float));
    float* us2      = (float*)alloc(N2SL * sizeof(float));
    float* uv2      = (float*)alloc(3 * N2SL * sizeof(float));
    float* us1      = (float*)alloc(N1SL * sizeof(float));
    float* uv1      = (float*)alloc(3 * N1SL * sizeof(float));
    int* sorted     = (int*)alloc(SCAP * sizeof(int));
    int* species    = (int*)alloc(B_NODES * sizeof(int));
    int* cnt_part   = (int*)alloc(NHB * S_SPEC * sizeof(int));
    int* cnt_final  = (int*)alloc(S_SPEC * sizeof(int));
    int* cursor     = (int*)alloc(S_SPEC * sizeof(int));

    int prep_blocks = NHB + (4 * NUSYM + 255) / 256;   // 64 + 64
    hipLaunchKernelGGL(k_prep, dim3(prep_blocks), dim3(256), 0, stream,
                       y, U3s, U2s, U1s, U3v, U2v, U1v,
                       species, cnt_part, cursor,
                       us3, uv3, us2, uv2, us1, uv1);

    int mid_blocks = B_NODES / 256 + (TBL_THREADS + 255) / 256;   // 64 + 548
    hipLaunchKernelGGL(k_mid, dim3(mid_blocks), dim3(256), 0, stream,
                       species, cnt_part, cnt_final, cursor, sorted,
                       W3s, W2s, W1s, W3v, W2v, W1v,
                       us3, uv3, us2, uv2, us1, uv1, table);

    hipLaunchKernelGGL(k_main, dim3(NROUND * 8 * 64), dim3(256), 0, stream,
                       x, table, sorted, cnt_final, out);
}

// Round 22
// 87.968 us; speedup vs baseline: 1.3183x; 1.3183x over previous
//
#include <hip/hip_runtime.h>
#include <cstdint>

#define B_NODES 16384
#define C_CH    64
#define I_DIM   9
#define S_SPEC  10
#define K3C     23
#define K2C     5
#define K1C     2
#define NTRI    165
#define NPAIR   45
#define NSING   9
#define NIDX    (NTRI + NPAIR + NSING)   // 219
#define TILE_N  256   // nodes per tile (= block); 1 node/thread (r16-proven)
#define MAXT    74    // <= B/256 + S
#define NROUND  10    // ceil(MAXT/8)
#define SCAP    (MAXT * TILE_N)
#define OUT_STRIDE (4 * C_CH)
#define NHB     64    // histogram blocks

#define N3SL (NTRI * K3C)    // 3795
#define N2SL (NPAIR * K2C)   // 225
#define N1SL (NSING * K1C)   // 18
#define NUSYM (N3SL + N2SL + N1SL)  // 4038
#define TBL_THREADS (S_SPEC * C_CH * NIDX)   // 140160

typedef float v2f __attribute__((ext_vector_type(2)));
typedef float v4f __attribute__((ext_vector_type(4)));

// ============ kernel 1: prep (blocks 0..63: hist-partials; blocks 64..: usym) ============

__global__ __launch_bounds__(256) void k_prep(
        const float* __restrict__ y,
        const float* __restrict__ U3s, const float* __restrict__ U2s,
        const float* __restrict__ U1s,
        const float* __restrict__ U3v, const float* __restrict__ U2v,
        const float* __restrict__ U1v,
        int* __restrict__ species, int* __restrict__ cnt_part,
        int* __restrict__ cursor,
        float* __restrict__ us3, float* __restrict__ uv3,
        float* __restrict__ us2, float* __restrict__ uv2,
        float* __restrict__ us1, float* __restrict__ uv1) {
    int tid = threadIdx.x;
    if (blockIdx.x < NHB) {
        __shared__ int hcnt[S_SPEC];
        if (tid < S_SPEC) hcnt[tid] = 0;
        __syncthreads();
        int i = blockIdx.x * (B_NODES / NHB) + tid;   // chunk = 256 = blockDim
        {
            int e = 0; float best = -1.f;
            #pragma unroll
            for (int j = 0; j < S_SPEC; ++j) {
                float v = y[i * S_SPEC + j];
                if (v > best) { best = v; e = j; }
            }
            species[i] = e;
            atomicAdd(&hcnt[e], 1);
        }
        __syncthreads();
        if (tid < S_SPEC) cnt_part[blockIdx.x * S_SPEC + tid] = hcnt[tid];
        return;
    }
    // ---- usym blocks: 4*NUSYM threads, m = segment ----
    if (blockIdx.x == NHB && tid < S_SPEC) cursor[tid] = 0;
    int tt = (blockIdx.x - NHB) * 256 + tid;
    if (tt >= 4 * NUSYM) return;
    int m = tt / NUSYM;
    int t = tt - m * NUSYM;

    if (t < N3SL) {
        int idx = t / K3C, k = t % K3C;
        int p = 0, q = 0, r = 0, cum = 0;
        for (int p0 = 0; p0 < 9; ++p0)
            for (int q0 = p0; q0 < 9; ++q0)
                for (int r0 = q0; r0 < 9; ++r0) {
                    if (cum == idx) { p = p0; q = q0; r = r0; }
                    ++cum;
                }
        const float* src = (m == 0) ? U3s : (U3v + (size_t)(m - 1) * 729 * K3C);
        int perm[6][3] = {{p,q,r},{p,r,q},{q,p,r},{q,r,p},{r,p,q},{r,q,p}};
        float a0 = 0.f;
        for (int j = 0; j < 6; ++j) {
            bool dup = false;
            for (int j2 = 0; j2 < j; ++j2)
                if (perm[j2][0]==perm[j][0] && perm[j2][1]==perm[j][1] && perm[j2][2]==perm[j][2])
                    dup = true;
            if (dup) continue;
            int a = perm[j][0], bb = perm[j][1], i = perm[j][2];
            a0 += src[((a * 9 + bb) * 9 + i) * K3C + k];
        }
        float* dst = (m == 0) ? us3 : (uv3 + (size_t)(m - 1) * N3SL);
        dst[t] = a0;
    } else if (t < N3SL + N2SL) {
        int t2 = t - N3SL;
        int idx = t2 / K2C, k = t2 % K2C;
        int p = 0, q = 0, cum = 0;
        for (int p0 = 0; p0 < 9; ++p0)
            for (int q0 = p0; q0 < 9; ++q0) {
                if (cum == idx) { p = p0; q = q0; }
                ++cum;
            }
        const float* src = (m == 0) ? U2s : (U2v + (size_t)(m - 1) * 81 * K2C);
        float a0 = src[(p * 9 + q) * K2C + k];
        if (p != q) a0 += src[(q * 9 + p) * K2C + k];
        float* dst = (m == 0) ? us2 : (uv2 + (size_t)(m - 1) * N2SL);
        dst[t2] = a0;
    } else {
        int t1 = t - N3SL - N2SL;
        const float* src = (m == 0) ? U1s : (U1v + (size_t)(m - 1) * 9 * K1C);
        float* dst = (m == 0) ? us1 : (uv1 + (size_t)(m - 1) * N1SL);
        dst[t1] = src[t1];
    }
}

// ============ kernel 2: mid (blocks 0..63: scatter; rest: table build) ============

__global__ __launch_bounds__(256) void k_mid(
        const int* __restrict__ species, const int* __restrict__ cnt_part,
        int* __restrict__ cnt_final,
        int* __restrict__ cursor, int* __restrict__ sorted,
        const float* __restrict__ W3s, const float* __restrict__ W2s,
        const float* __restrict__ W1s,
        const float* __restrict__ W3v, const float* __restrict__ W2v,
        const float* __restrict__ W1v,
        const float* __restrict__ us3, const float* __restrict__ uv3,
        const float* __restrict__ us2, const float* __restrict__ uv2,
        const float* __restrict__ us1, const float* __restrict__ uv1,
        float* __restrict__ table) {
    int tid = threadIdx.x;
    if (blockIdx.x < B_NODES / 256) {
        __shared__ int scnt[S_SPEC], sseg[S_SPEC];
        if (tid < S_SPEC) {
            int s = 0;
            for (int w = 0; w < NHB; ++w) s += cnt_part[w * S_SPEC + tid];
            scnt[tid] = s;
            if (blockIdx.x == 0) cnt_final[tid] = s;
        }
        __syncthreads();
        if (tid == 0) {
            int run = 0;
            for (int j = 0; j < S_SPEC; ++j) {
                sseg[j] = run;
                run += ((scnt[j] + TILE_N - 1) / TILE_N) * TILE_N;
            }
        }
        __syncthreads();
        int b = blockIdx.x * 256 + tid;
        int e = species[b];
        int lane = tid & 63;
        unsigned long long lanebit = 1ull << lane;
        for (int j = 0; j < S_SPEC; ++j) {
            unsigned long long m = __ballot(e == j);
            if (m == 0ull) continue;
            int leader = __ffsll(m) - 1;
            int base = 0;
            if (lane == leader) base = atomicAdd(&cursor[j], __popcll(m));
            base = __shfl(base, leader);
            if (e == j) {
                int pos = base + __popcll(m & (lanebit - 1ull));
                sorted[sseg[j] + pos] = b;
            }
        }
        return;
    }
    // ---- table build: t = (e*64 + c)*NIDX + row; lanes span row ----
    int t = (blockIdx.x - B_NODES / 256) * 256 + tid;
    if (t >= TBL_THREADS) return;
    int row = t % NIDX;
    int ec  = t / NIDX;
    int c = ec & (C_CH - 1), e = ec >> 6;

    int type = -1, pp = 0, pidx = 0, tidx = 0;
    {
        int cum = 0, pcount = 0, tcount = 0;
        for (int p0 = 0; p0 < 9; ++p0) {
            if (cum == row) { type = 0; pp = p0; }
            ++cum;
            for (int q0 = p0; q0 < 9; ++q0) {
                if (cum == row) { type = 1; pidx = pcount; }
                ++cum; ++pcount;
                for (int r0 = q0; r0 < 9; ++r0) {
                    if (cum == row) { type = 2; tidx = tcount; }
                    ++cum; ++tcount;
                }
            }
        }
    }

    float acc0 = 0.f, acc1 = 0.f, acc2 = 0.f, acc3 = 0.f;
    if (type == 2) {
        const float* u0 = us3 + tidx * K3C;
        const float* u1 = uv3 + 0 * N3SL + tidx * K3C;
        const float* u2 = uv3 + 1 * N3SL + tidx * K3C;
        const float* u3 = uv3 + 2 * N3SL + tidx * K3C;
        const float* Ws = W3s + (size_t)e * K3C * C_CH + c;
        const float* Wv = W3v + (size_t)e * K3C * C_CH + c;
        #pragma unroll
        for (int k = 0; k < K3C; ++k) {
            float ws = Ws[k * C_CH], wv = Wv[k * C_CH];
            acc0 += u0[k] * ws;
            acc1 += u1[k] * wv;
            acc2 += u2[k] * wv;
            acc3 += u3[k] * wv;
        }
    } else if (type == 1) {
        const float* u0 = us2 + pidx * K2C;
        const float* u1 = uv2 + 0 * N2SL + pidx * K2C;
        const float* u2 = uv2 + 1 * N2SL + pidx * K2C;
        const float* u3 = uv2 + 2 * N2SL + pidx * K2C;
        const float* Ws = W2s + (size_t)e * K2C * C_CH + c;
        const float* Wv = W2v + (size_t)e * K2C * C_CH + c;
        #pragma unroll
        for (int k = 0; k < K2C; ++k) {
            float ws = Ws[k * C_CH], wv = Wv[k * C_CH];
            acc0 += u0[k] * ws;
            acc1 += u1[k] * wv;
            acc2 += u2[k] * wv;
            acc3 += u3[k] * wv;
        }
    } else {
        const float* u0 = us1 + pp * K1C;
        const float* u1 = uv1 + 0 * N1SL + pp * K1C;
        const float* u2 = uv1 + 1 * N1SL + pp * K1C;
        const float* u3 = uv1 + 2 * N1SL + pp * K1C;
        const float* Ws = W1s + (size_t)e * K1C * C_CH + c;
        const float* Wv = W1v + (size_t)e * K1C * C_CH + c;
        #pragma unroll
        for (int k = 0; k < K1C; ++k) {
            float ws = Ws[k * C_CH], wv = Wv[k * C_CH];
            acc0 += u0[k] * ws;
            acc1 += u1[k] * wv;
            acc2 += u2[k] * wv;
            acc3 += u3[k] * wv;
        }
    }
    *(v4f*)(table + (size_t)t * 4) = (v4f){acc0, acc1, acc2, acc3};
}

// ============ kernel 3: main polynomial evaluation (r16-proven body) ============
// DS-pipe floor: 74 waves/CU x 219 broadcast ds_read_b128 x ~8.4cyc ~= 54us.
// All structural escapes measured and refuted (r12-r17 2-node regalloc
// pathology; r20 SMEM tail shares lgkmcnt; r21 VMEM tail per-use latency).

__global__ __launch_bounds__(256) void k_main(
        const float* __restrict__ x, const float* __restrict__ table,
        const int* __restrict__ sorted, const int* __restrict__ cnt,
        float* __restrict__ out) {
    __shared__ float xs[TILE_N * 9];   // 9.2KB
    __shared__ v4f   ts[NIDX];         // 3.5KB table slice

    int f = blockIdx.x;
    int xcd = f & 7;
    int j = f >> 3;                    // 0 .. NROUND*64-1
    int t = (j >> 6) * 8 + xcd;        // tiles round-robin across XCDs
    int c = j & 63;
    // derive tile species + valid count from cnt (wave-uniform 10-iter prefix)
    int e = -1, run = 0, tstart = 0, ecnt = 0;
    #pragma unroll
    for (int s = 0; s < S_SPEC; ++s) {
        int cs = cnt[s];
        int tiles = (cs + TILE_N - 1) / TILE_N;
        if (t >= run && t < run + tiles) { e = s; tstart = run; ecnt = cs; }
        run += tiles;
    }
    if (e < 0) return;
    int valid = ecnt - (t - tstart) * TILE_N;
    if (valid > TILE_N) valid = TILE_N;
    int tid = threadIdx.x;

    // stage table slice: 219 coalesced 16B loads
    const v4f* __restrict__ Tg = (const v4f*)table + (size_t)(e * C_CH + c) * NIDX;
    if (tid < NIDX) ts[tid] = Tg[tid];

    // stage x: per node 36B contiguous
    for (int s = tid; s < TILE_N * 9; s += 256) {
        int n = s / 9, i = s - n * 9;
        float v = 0.f;
        if (n < valid) {
            int b = sorted[t * TILE_N + n];
            v = x[((size_t)b * C_CH + c) * I_DIM + i];
        }
        xs[n * 9 + i] = v;   // stride 9, gcd(9,32)=1 -> conflict-free
    }
    __syncthreads();

    float xr[9];
    #pragma unroll
    for (int i = 0; i < 9; ++i) xr[i] = xs[tid * 9 + i];

    v2f a01 = {0.f, 0.f}, a23 = {0.f, 0.f};
    int tix = 0;
    #pragma unroll
    for (int p = 0; p < 9; ++p) {
        {
            v4f rs = ts[tix]; ++tix;
            a01 += (v2f){rs[0], rs[1]} * xr[p];
            a23 += (v2f){rs[2], rs[3]} * xr[p];
        }
        #pragma unroll
        for (int q = p; q < 9; ++q) {
            float m2 = xr[p] * xr[q];
            v4f rp = ts[tix]; ++tix;
            a01 += (v2f){rp[0], rp[1]} * m2;
            a23 += (v2f){rp[2], rp[3]} * m2;
            #pragma unroll
            for (int r = q; r < 9; ++r) {
                float m3 = m2 * xr[r];
                v4f rt = ts[tix]; ++tix;
                a01 += (v2f){rt[0], rt[1]} * m3;
                a23 += (v2f){rt[2], rt[3]} * m3;
            }
        }
    }

    if (tid >= valid) return;
    int b = sorted[t * TILE_N + tid];
    out[(size_t)b * OUT_STRIDE + c] = a01.x;
    float* ov = out + (size_t)b * OUT_STRIDE + C_CH + c * 3;
    ov[0] = a01.y; ov[1] = a23.x; ov[2] = a23.y;
}

// ============ launcher: 3 kernels, no memsets ============

extern "C" void kernel_launch(void* const* d_in, const int* in_sizes, int n_in,
                              void* d_out, int out_size, void* d_ws, size_t ws_size,
                              hipStream_t stream) {
    const float* x   = (const float*)d_in[0];
    const float* y   = (const float*)d_in[1];
    const float* U3s = (const float*)d_in[2];
    const float* U2s = (const float*)d_in[3];
    const float* U1s = (const float*)d_in[4];
    const float* W3s = (const float*)d_in[5];
    const float* W2s = (const float*)d_in[6];
    const float* W1s = (const float*)d_in[7];
    const float* U3v = (const float*)d_in[8];
    const float* U2v = (const float*)d_in[9];
    const float* U1v = (const float*)d_in[10];
    const float* W3v = (const float*)d_in[11];
    const float* W2v = (const float*)d_in[12];
    const float* W1v = (const float*)d_in[13];
    float* out = (float*)d_out;

    char* ws = (char*)d_ws;
    size_t off = 0;
    auto alloc = [&](size_t bytes) -> char* {
        char* p = ws + off;
        off = (off + bytes + 255) & ~(size_t)255;
        return p;
    };
    float* table    = (float*)alloc((size_t)S_SPEC * C_CH * NIDX * 4 * sizeof(float));
    float* us3      = (float*)alloc(N3SL * sizeof(float));
    float* uv3      = (float*)alloc(3 * N3SL * sizeof(float));
    float* us2      = (float*)alloc(N2SL * sizeof(float));
    float* uv2      = (float*)alloc(3 * N2SL * sizeof(float));
    float* us1      = (float*)alloc(N1SL * sizeof(float));
    float* uv1      = (float*)alloc(3 * N1SL * sizeof(float));
    int* sorted     = (int*)alloc(SCAP * sizeof(int));
    int* species    = (int*)alloc(B_NODES * sizeof(int));
    int* cnt_part   = (int*)alloc(NHB * S_SPEC * sizeof(int));
    int* cnt_final  = (int*)alloc(S_SPEC * sizeof(int));
    int* cursor     = (int*)alloc(S_SPEC * sizeof(int));

    int prep_blocks = NHB + (4 * NUSYM + 255) / 256;   // 64 + 64
    hipLaunchKernelGGL(k_prep, dim3(prep_blocks), dim3(256), 0, stream,
                       y, U3s, U2s, U1s, U3v, U2v, U1v,
                       species, cnt_part, cursor,
                       us3, uv3, us2, uv2, us1, uv1);

    int mid_blocks = B_NODES / 256 + (TBL_THREADS + 255) / 256;   // 64 + 548
    hipLaunchKernelGGL(k_mid, dim3(mid_blocks), dim3(256), 0, stream,
                       species, cnt_part, cnt_final, cursor, sorted,
                       W3s, W2s, W1s, W3v, W2v, W1v,
                       us3, uv3, us2, uv2, us1, uv1, table);

    hipLaunchKernelGGL(k_main, dim3(NROUND * 8 * 64), dim3(256), 0, stream,
                       x, table, sorted, cnt_final, out);
}